// Round 13
// baseline (950.506 us; speedup 1.0000x reference)
//
#include <hip/hip_runtime.h>
#include <math.h>

#define N_NODES 40000
#define N_EDGES 640000
#define FGRP 8
#define FRANGE (N_NODES / FGRP)     // 5000 (gather row permutation only)
#define FB 96                       // fill blocks (LDS counting sort)
#define DR 417                      // dsts per fill block (96*417 = 40032 >= 40000)
#define FCAP 8192                   // staging cap: mean 6672 + pad <= 625, +~11 sigma slack
#define NCOMBO 10168                // 10000 LN blocks + 168 weight blocks

typedef __attribute__((ext_vector_type(8))) short short8;   // 8 bf16 (A/B frag)
typedef __attribute__((ext_vector_type(4))) float f32x4;    // C/D frag

__device__ __forceinline__ unsigned short f2bf(float f) {
    union { float f; unsigned u; } v; v.f = f;
    unsigned r = (v.u + 0x7FFFu + ((v.u >> 16) & 1u)) >> 16;  // RNE
    return (unsigned short)r;
}
__device__ __forceinline__ float bf2f(unsigned short h) {
    union { unsigned u; float f; } v; v.u = ((unsigned)h) << 16;
    return v.f;
}

__device__ __forceinline__ float wave_sum(float v) {
    #pragma unroll
    for (int m = 1; m < 64; m <<= 1) v += __shfl_xor(v, m, 64);
    return v;
}
__device__ __forceinline__ float wave_max(float v) {
    #pragma unroll
    for (int m = 1; m < 64; m <<= 1) v = fmaxf(v, __shfl_xor(v, m, 64));
    return v;
}

// blocks [0,FB): LDS counting-sort fill — block owns dsts [bid*DR, bid*DR+DR).
//   Stage in-range edges in LDS, histogram, padded scan (4-entry-aligned starts
//   -> 16B-aligned gather rows), then burst-write the sorted 32KB region
//   (single writer, tight window -> L2 write-combines to full lines; kills the
//   ~26MB partial-line RMW amplification of the scatter fill). No global atomics.
// blocks [FB, FB+NCOMBO): combo (LN0 rows -> bf16 h0, weight transpose+split).
// Fill blocks sit at the FRONT of the grid so all 96 start immediately and run
// concurrent with combo (fill ~17us hides under combo ~25us).
__global__ __launch_bounds__(256) void comboSortFill_kernel(const float* __restrict__ x,
        const float* __restrict__ g, const float* __restrict__ b,
        unsigned short* __restrict__ h0h,
        const float* __restrict__ W0l, const float* __restrict__ W0r,
        const float* __restrict__ W1l, const float* __restrict__ W1r,
        unsigned short* __restrict__ Wt1h, unsigned short* __restrict__ Wt1l,
        unsigned short* __restrict__ Wt2h, unsigned short* __restrict__ Wt2l,
        const int* __restrict__ ei, const float* __restrict__ ew,
        int* __restrict__ cnt, int* __restrict__ rs, unsigned int* __restrict__ sPk) {
    __shared__ unsigned int   stage_pk[FCAP];   // 32 KB
    __shared__ unsigned short stage_d[FCAP];    // 16 KB
    __shared__ int hist[512];                   // 2 KB (becomes cursor after scan)
    __shared__ int off[512];                    // 2 KB
    __shared__ int nstage;
    int bid = blockIdx.x, tid = threadIdx.x;
    if (bid < FB) {
        int lo = bid * DR;
        for (int t = tid; t < 512; t += 256) hist[t] = 0;
        if (tid == 0) nstage = 0;
        __syncthreads();
        // 1. stage in-range edges (dst column read coalesced; src/w loads rare)
        for (int e = tid; e < N_EDGES; e += 256) {
            int d = ei[N_EDGES + e];
            if (d >= lo && d < lo + DR) {
                int pos = atomicAdd(&nstage, 1);
                if (pos < FCAP) {
                    stage_pk[pos] = (unsigned int)ei[e] | ((unsigned int)f2bf(ew[e]) << 16);
                    stage_d[pos]  = (unsigned short)(d - lo);
                }
            }
        }
        __syncthreads();
        int ns = nstage; if (ns > FCAP) ns = FCAP;
        // 2. histogram from staged entries
        for (int i = tid; i < ns; i += 256) atomicAdd(&hist[stage_d[i]], 1);
        __syncthreads();
        // 3. inclusive scan of 4-padded sizes (Hillis-Steele over 512, 256 thr)
        for (int t = tid; t < 512; t += 256) off[t] = (hist[t] + 3) & ~3;
        __syncthreads();
        for (int st = 1; st < 512; st <<= 1) {
            int v0 = (tid >= st) ? off[tid - st] : 0;
            int v1 = (tid + 256 >= st) ? off[tid + 256 - st] : 0;
            __syncthreads();
            off[tid] += v0;
            off[tid + 256] += v1;
            __syncthreads();
        }
        // 4. per-dst start, cnt/rs global writes, hist -> cursor
        int base = bid * FCAP;
        for (int t = tid; t < DR; t += 256) {
            int h = hist[t];
            int start = off[t] - ((h + 3) & ~3);
            if (lo + t < N_NODES) {
                cnt[lo + t] = h;
                rs[lo + t] = base + start;
            }
            hist[t] = start;                    // cursor
        }
        __syncthreads();
        // 5. sorted burst-write into private region (write-combined)
        for (int i = tid; i < ns; i += 256) {
            int d = stage_d[i];
            int pos = atomicAdd(&hist[d], 1);
            sPk[base + pos] = stage_pk[i];
        }
    } else {
        int cb = bid - FB;                      // 0..NCOMBO-1
        if (cb < 10000) {
            int row = cb * 4 + (threadIdx.x >> 6);
            int lane = threadIdx.x & 63;
            float2 v = ((const float2*)(x + (size_t)row * 128))[lane];
            float mu = wave_sum(v.x + v.y) * (1.0f / 128.0f);
            float dx = v.x - mu, dy = v.y - mu;
            float var = wave_sum(dx * dx + dy * dy) * (1.0f / 128.0f);
            float rsq = rsqrtf(var + 1e-5f);
            float2 gv = ((const float2*)g)[lane];
            float2 bv = ((const float2*)b)[lane];
            ushort2 hv;
            hv.x = f2bf(dx * rsq * gv.x + bv.x);
            hv.y = f2bf(dy * rsq * gv.y + bv.y);
            ((ushort2*)(h0h + (size_t)row * 128))[lane] = hv;
        } else {
            int i = (cb - 10000) * 256 + threadIdx.x;   // 0..43007
            float w; unsigned short *ph2, *pl; int idx;
            if (i < 256 * 128) {
                int c = i >> 7, k = i & 127;
                w = (c < 128) ? W0l[c * 128 + k] : W0r[(c - 128) * 128 + k];
                ph2 = Wt1h; pl = Wt1l; idx = i;
            } else {
                int j = i - 256 * 128;
                int c = j >> 7, k = j & 127;
                w = (c < 40) ? W1l[c * 128 + k] : W1r[(c - 40) * 128 + k];
                ph2 = Wt2h; pl = Wt2l; idx = j;
            }
            unsigned short hi = f2bf(w);
            ph2[idx] = hi;
            pl[idx] = f2bf(w - bf2f(hi));
        }
    }
}

// ---------------- MFMA GEMMs, B staged in LDS (XOR-swizzled) ----------------
// LDS element (c,k) at byte (c*256 + k*2) ^ ((c&7)<<4).
// C/D: col = lane&15, row = (lane>>4)*4 + reg   [HW-verified]

// bf16x2 (Ah·Bh + Ah·Bl): hl(bf16,+bias) cols 0..127; agg(bf16) cols 128..255
__global__ __launch_bounds__(256) void gemm1_kernel(
        const unsigned short* __restrict__ h0h,
        const unsigned short* __restrict__ Wt1h, const unsigned short* __restrict__ Wt1l,
        const float* __restrict__ b0l,
        unsigned short* __restrict__ hl, unsigned short* __restrict__ agg) {
    __shared__ unsigned short Bs[2][128 * 128];   // 64 KB
    int tid = threadIdx.x;
    int cBase = blockIdx.y * 128;
    #pragma unroll
    for (int plane = 0; plane < 2; ++plane) {
        const unsigned short* src = plane ? Wt1l : Wt1h;
        char* dst = (char*)Bs[plane];
        #pragma unroll
        for (int i = 0; i < 8; ++i) {
            int gid = i * 256 + tid;
            int c = gid >> 4, kc = gid & 15;
            short8 v = *(const short8*)(src + (size_t)(cBase + c) * 128 + kc * 8);
            int byte = (c * 256 + kc * 16) ^ ((c & 7) << 4);
            *(short8*)(dst + byte) = v;
        }
    }
    __syncthreads();

    int wid = tid >> 6, lane = tid & 63;
    int rBase = (blockIdx.x * 4 + wid) * 32;
    if (rBase < N_NODES) {
        int lr = lane & 15;
        int lk = (lane >> 4) * 8;
        int sw = (lr & 7) << 4;
        const unsigned short* a0h = h0h + (size_t)(rBase + lr) * 128 + lk;
        const unsigned short* a1h = a0h + 16 * 128;
        f32x4 acc[2][8] = {};
        #pragma unroll
        for (int ks = 0; ks < 4; ++ks) {
            int kb = ks * 32;
            short8 A0h = *(const short8*)(a0h + kb);
            short8 A1h = *(const short8*)(a1h + kb);
            #pragma unroll
            for (int ct = 0; ct < 8; ++ct) {
                int bb = (((ct * 16 + lr) << 8) + (ks << 6) + ((lane >> 4) << 4)) ^ sw;
                short8 Bh = *(const short8*)((const char*)Bs[0] + bb);
                short8 Bl = *(const short8*)((const char*)Bs[1] + bb);
                acc[0][ct] = __builtin_amdgcn_mfma_f32_16x16x32_bf16(A0h, Bh, acc[0][ct], 0, 0, 0);
                acc[0][ct] = __builtin_amdgcn_mfma_f32_16x16x32_bf16(A0h, Bl, acc[0][ct], 0, 0, 0);
                acc[1][ct] = __builtin_amdgcn_mfma_f32_16x16x32_bf16(A1h, Bh, acc[1][ct], 0, 0, 0);
                acc[1][ct] = __builtin_amdgcn_mfma_f32_16x16x32_bf16(A1h, Bl, acc[1][ct], 0, 0, 0);
            }
        }
        int orow = (lane >> 4) * 4;
        #pragma unroll
        for (int rt = 0; rt < 2; ++rt) {
            int row = rBase + rt * 16 + orow;
            #pragma unroll
            for (int ct = 0; ct < 8; ++ct) {
                int col = cBase + ct * 16 + lr;
                if (col < 128) {
                    float bias = b0l[col];
                    #pragma unroll
                    for (int j = 0; j < 4; ++j)
                        hl[(size_t)(row + j) * 128 + col] = f2bf(acc[rt][ct][j] + bias);
                } else {
                    int cc = col - 128;
                    #pragma unroll
                    for (int j = 0; j < 4; ++j)
                        agg[(size_t)(row + j) * 128 + cc] = f2bf(acc[rt][ct][j]);
                }
            }
        }
    }
}

// layer-2 keeps bf16x3 (h2 hi/lo): gl(bf16,+bias) cols 0..39; agg2(bf16) cols 40..79
__global__ __launch_bounds__(256) void gemm2_kernel(
        const unsigned short* __restrict__ h2h, const unsigned short* __restrict__ h2l,
        const unsigned short* __restrict__ Wt2h, const unsigned short* __restrict__ Wt2l,
        const float* __restrict__ b1l,
        unsigned short* __restrict__ gl, unsigned short* __restrict__ agg2) {
    __shared__ unsigned short Bs[2][80 * 128];    // 40 KB
    int tid = threadIdx.x;
    #pragma unroll
    for (int plane = 0; plane < 2; ++plane) {
        const unsigned short* src = plane ? Wt2l : Wt2h;
        char* dst = (char*)Bs[plane];
        #pragma unroll
        for (int i = 0; i < 5; ++i) {
            int gid = i * 256 + tid;
            int c = gid >> 4, kc = gid & 15;
            short8 v = *(const short8*)(src + (size_t)c * 128 + kc * 8);
            int byte = (c * 256 + kc * 16) ^ ((c & 7) << 4);
            *(short8*)(dst + byte) = v;
        }
    }
    __syncthreads();

    int wid = tid >> 6, lane = tid & 63;
    int rBase = (blockIdx.x * 4 + wid) * 32;
    if (rBase < N_NODES) {
        int lr = lane & 15;
        int lk = (lane >> 4) * 8;
        int sw = (lr & 7) << 4;
        const unsigned short* a0h = h2h + (size_t)(rBase + lr) * 128 + lk;
        const unsigned short* a0l = h2l + (size_t)(rBase + lr) * 128 + lk;
        const unsigned short* a1h = a0h + 16 * 128;
        const unsigned short* a1l = a0l + 16 * 128;
        f32x4 acc[2][5] = {};
        #pragma unroll
        for (int ks = 0; ks < 4; ++ks) {
            int kb = ks * 32;
            short8 A0h = *(const short8*)(a0h + kb);
            short8 A0l = *(const short8*)(a0l + kb);
            short8 A1h = *(const short8*)(a1h + kb);
            short8 A1l = *(const short8*)(a1l + kb);
            #pragma unroll
            for (int ct = 0; ct < 5; ++ct) {
                int bb = (((ct * 16 + lr) << 8) + (ks << 6) + ((lane >> 4) << 4)) ^ sw;
                short8 Bh = *(const short8*)((const char*)Bs[0] + bb);
                short8 Bl = *(const short8*)((const char*)Bs[1] + bb);
                acc[0][ct] = __builtin_amdgcn_mfma_f32_16x16x32_bf16(A0h, Bh, acc[0][ct], 0, 0, 0);
                acc[0][ct] = __builtin_amdgcn_mfma_f32_16x16x32_bf16(A0h, Bl, acc[0][ct], 0, 0, 0);
                acc[0][ct] = __builtin_amdgcn_mfma_f32_16x16x32_bf16(A0l, Bh, acc[0][ct], 0, 0, 0);
                acc[1][ct] = __builtin_amdgcn_mfma_f32_16x16x32_bf16(A1h, Bh, acc[1][ct], 0, 0, 0);
                acc[1][ct] = __builtin_amdgcn_mfma_f32_16x16x32_bf16(A1h, Bl, acc[1][ct], 0, 0, 0);
                acc[1][ct] = __builtin_amdgcn_mfma_f32_16x16x32_bf16(A1l, Bh, acc[1][ct], 0, 0, 0);
            }
        }
        int orow = (lane >> 4) * 4;
        #pragma unroll
        for (int rt = 0; rt < 2; ++rt) {
            int row = rBase + rt * 16 + orow;
            #pragma unroll
            for (int ct = 0; ct < 5; ++ct) {
                int col = ct * 16 + lr;   // 0..79
                if (col < 40) {
                    float bias = b1l[col];
                    #pragma unroll
                    for (int j = 0; j < 4; ++j)
                        gl[(size_t)(row + j) * 40 + col] = f2bf(acc[rt][ct][j] + bias);
                } else {
                    int cc = col - 40;
                    #pragma unroll
                    for (int j = 0; j < 4; ++j)
                        agg2[(size_t)(row + j) * 40 + cc] = f2bf(acc[rt][ct][j]);
                }
            }
        }
    }
}

__device__ __forceinline__ void g1_edge(const unsigned short* __restrict__ hl,
        unsigned int pk, int lane, float2* acc) {
    ushort2 u = ((const ushort2*)(hl + (size_t)(pk & 0xFFFF) * 128))[lane];
    float w = bf2f((unsigned short)(pk >> 16));
    acc->x = fmaf(bf2f(u.x), w, acc->x);
    acc->y = fmaf(bf2f(u.y), w, acc->y);
}

// gather (compact sorted segments) + fused l2norm+LN+relu -> split-bf16 h2
__global__ __launch_bounds__(256) void gather1_kernel(const int* __restrict__ cnt,
        const int* __restrict__ rs, const unsigned int* __restrict__ sPk,
        const unsigned short* __restrict__ hl, const unsigned short* __restrict__ agg,
        const float* __restrict__ g, const float* __restrict__ b,
        unsigned short* __restrict__ h2h, unsigned short* __restrict__ h2l) {
    int bid = blockIdx.x;
    int row = (bid & 7) * FRANGE + (bid >> 3) * 4 + (threadIdx.x >> 6);
    int lane = threadIdx.x & 63;
    int n = cnt[row];
    const unsigned int* ep = sPk + rs[row];     // 16B-aligned (4-padded starts)
    ushort2 r0 = ((const ushort2*)(agg + (size_t)row * 128))[lane];   // root (bf16)
    float2 acc; acc.x = bf2f(r0.x); acc.y = bf2f(r0.y);
    int e = 0;
    for (; e + 8 <= n; e += 8) {
        uint4 q0 = *(const uint4*)(ep + e);
        uint4 q1 = *(const uint4*)(ep + e + 4);
        g1_edge(hl, q0.x, lane, &acc); g1_edge(hl, q0.y, lane, &acc);
        g1_edge(hl, q0.z, lane, &acc); g1_edge(hl, q0.w, lane, &acc);
        g1_edge(hl, q1.x, lane, &acc); g1_edge(hl, q1.y, lane, &acc);
        g1_edge(hl, q1.z, lane, &acc); g1_edge(hl, q1.w, lane, &acc);
    }
    if (e + 4 <= n) {
        uint4 q0 = *(const uint4*)(ep + e);
        g1_edge(hl, q0.x, lane, &acc); g1_edge(hl, q0.y, lane, &acc);
        g1_edge(hl, q0.z, lane, &acc); g1_edge(hl, q0.w, lane, &acc);
        e += 4;
    }
    for (; e < n; ++e) g1_edge(hl, ep[e], lane, &acc);
    float nrm = sqrtf(wave_sum(acc.x * acc.x + acc.y * acc.y));
    float inv = 1.0f / fmaxf(nrm, 1e-12f);
    float vx = acc.x * inv, vy = acc.y * inv;
    float mu = wave_sum(vx + vy) * (1.0f / 128.0f);
    float dx = vx - mu, dy = vy - mu;
    float var = wave_sum(dx * dx + dy * dy) * (1.0f / 128.0f);
    float rsq = rsqrtf(var + 1e-5f);
    float2 gv = ((const float2*)g)[lane];
    float2 bv = ((const float2*)b)[lane];
    float ox = fmaxf(dx * rsq * gv.x + bv.x, 0.0f);
    float oy = fmaxf(dy * rsq * gv.y + bv.y, 0.0f);
    ushort2 hv, lv;
    hv.x = f2bf(ox); hv.y = f2bf(oy);
    lv.x = f2bf(ox - bf2f(hv.x)); lv.y = f2bf(oy - bf2f(hv.y));
    ((ushort2*)(h2h + (size_t)row * 128))[lane] = hv;
    ((ushort2*)(h2l + (size_t)row * 128))[lane] = lv;
}

// gather (compact sorted segments) + fused l2norm + log_softmax
__global__ __launch_bounds__(256) void gather2_kernel(const int* __restrict__ cnt,
        const int* __restrict__ rs, const unsigned int* __restrict__ sPk,
        const unsigned short* __restrict__ gl, const unsigned short* __restrict__ agg2,
        float* __restrict__ out) {
    int bid = blockIdx.x;
    int row = (bid & 7) * FRANGE + (bid >> 3) * 4 + (threadIdx.x >> 6);
    int lane = threadIdx.x & 63;
    bool act = lane < 40;
    int n = cnt[row];
    const unsigned int* ep = sPk + rs[row];
    float acc = act ? bf2f(agg2[(size_t)row * 40 + lane]) : 0.0f;  // root (bf16)
    int e = 0;
    for (; e + 8 <= n; e += 8) {
        uint4 q0 = *(const uint4*)(ep + e);
        uint4 q1 = *(const uint4*)(ep + e + 4);
        if (act) {
            float v0 = bf2f(gl[(size_t)(q0.x & 0xFFFF) * 40 + lane]);
            float v1 = bf2f(gl[(size_t)(q0.y & 0xFFFF) * 40 + lane]);
            float v2 = bf2f(gl[(size_t)(q0.z & 0xFFFF) * 40 + lane]);
            float v3 = bf2f(gl[(size_t)(q0.w & 0xFFFF) * 40 + lane]);
            float v4 = bf2f(gl[(size_t)(q1.x & 0xFFFF) * 40 + lane]);
            float v5 = bf2f(gl[(size_t)(q1.y & 0xFFFF) * 40 + lane]);
            float v6 = bf2f(gl[(size_t)(q1.z & 0xFFFF) * 40 + lane]);
            float v7 = bf2f(gl[(size_t)(q1.w & 0xFFFF) * 40 + lane]);
            acc = fmaf(v0, bf2f((unsigned short)(q0.x >> 16)), acc);
            acc = fmaf(v1, bf2f((unsigned short)(q0.y >> 16)), acc);
            acc = fmaf(v2, bf2f((unsigned short)(q0.z >> 16)), acc);
            acc = fmaf(v3, bf2f((unsigned short)(q0.w >> 16)), acc);
            acc = fmaf(v4, bf2f((unsigned short)(q1.x >> 16)), acc);
            acc = fmaf(v5, bf2f((unsigned short)(q1.y >> 16)), acc);
            acc = fmaf(v6, bf2f((unsigned short)(q1.z >> 16)), acc);
            acc = fmaf(v7, bf2f((unsigned short)(q1.w >> 16)), acc);
        }
    }
    if (e + 4 <= n) {
        uint4 q0 = *(const uint4*)(ep + e);
        if (act) {
            float v0 = bf2f(gl[(size_t)(q0.x & 0xFFFF) * 40 + lane]);
            float v1 = bf2f(gl[(size_t)(q0.y & 0xFFFF) * 40 + lane]);
            float v2 = bf2f(gl[(size_t)(q0.z & 0xFFFF) * 40 + lane]);
            float v3 = bf2f(gl[(size_t)(q0.w & 0xFFFF) * 40 + lane]);
            acc = fmaf(v0, bf2f((unsigned short)(q0.x >> 16)), acc);
            acc = fmaf(v1, bf2f((unsigned short)(q0.y >> 16)), acc);
            acc = fmaf(v2, bf2f((unsigned short)(q0.z >> 16)), acc);
            acc = fmaf(v3, bf2f((unsigned short)(q0.w >> 16)), acc);
        }
        e += 4;
    }
    for (; e < n; ++e) {
        unsigned int p = ep[e];
        if (act) {
            float v = bf2f(gl[(size_t)(p & 0xFFFF) * 40 + lane]);
            acc = fmaf(v, bf2f((unsigned short)(p >> 16)), acc);
        }
    }
    float nrm = sqrtf(wave_sum(act ? acc * acc : 0.0f));
    float o = acc / fmaxf(nrm, 1e-12f);
    float m = wave_max(act ? o : -INFINITY);
    float s = wave_sum(act ? expf(o - m) : 0.0f);
    float ls = logf(s);
    if (act) out[(size_t)row * 40 + lane] = o - m - ls;
}

extern "C" void kernel_launch(void* const* d_in, const int* in_sizes, int n_in,
                              void* d_out, int out_size, void* d_ws, size_t ws_size,
                              hipStream_t stream) {
    const float* x    = (const float*)d_in[0];
    const int*   ei   = (const int*)d_in[1];
    const float* ew   = (const float*)d_in[2];
    const float* ln0g = (const float*)d_in[3];
    const float* ln0b = (const float*)d_in[4];
    const float* W0l  = (const float*)d_in[5];
    const float* b0l  = (const float*)d_in[6];
    const float* W0r  = (const float*)d_in[7];
    const float* ln1g = (const float*)d_in[8];
    const float* ln1b = (const float*)d_in[9];
    const float* W1l  = (const float*)d_in[10];
    const float* b1l  = (const float*)d_in[11];
    const float* W1r  = (const float*)d_in[12];
    float* out = (float*)d_out;

    const size_t NBUF = (size_t)N_NODES * 128;  // 5.12M elems
    char* p = (char*)d_ws;
    auto alloc = [&](size_t bytes) { char* r = p; p += (bytes + 255) & ~(size_t)255; return r; };
    unsigned short* agg  = (unsigned short*)alloc(NBUF * 2); // agg / agg2 (bf16)
    unsigned short* hl   = (unsigned short*)alloc(NBUF * 2); // hl / gl (bf16)
    unsigned short* h0h  = (unsigned short*)alloc(NBUF * 2); // h0 (1 plane) / h2 hi
    unsigned short* h2l  = (unsigned short*)alloc(NBUF * 2); // h2 lo
    unsigned short* Wt1h = (unsigned short*)alloc(256 * 128 * 2);
    unsigned short* Wt1l = (unsigned short*)alloc(256 * 128 * 2);
    unsigned short* Wt2h = (unsigned short*)alloc(80 * 128 * 2);
    unsigned short* Wt2l = (unsigned short*)alloc(80 * 128 * 2);
    unsigned int*   sPk  = (unsigned int*)alloc((size_t)FB * FCAP * 4); // 3.1 MB sorted
    int*            cnt  = (int*)alloc(N_NODES * 4);
    int*            rs   = (int*)alloc(N_NODES * 4);
    unsigned short* gl   = hl;    // hl dead after gather1 (stride 40, 3.2MB L2-resident)
    unsigned short* agg2 = agg;   // agg dead after gather1

    // 1. fused LN0 + weight prep + LDS counting-sort fill (no memset, no atomics)
    comboSortFill_kernel<<<FB + NCOMBO, 256, 0, stream>>>(x, ln0g, ln0b, h0h,
            W0l, W0r, W1l, W1r, Wt1h, Wt1l, Wt2h, Wt2l, ei, ew, cnt, rs, sPk);
    // 2-5. pipeline
    gemm1_kernel<<<dim3(313, 2), 256, 0, stream>>>(h0h, Wt1h, Wt1l, b0l, hl, agg);
    gather1_kernel<<<N_NODES / 4, 256, 0, stream>>>(cnt, rs, sPk, hl, agg,
                                                    ln1g, ln1b, h0h, h2l);
    gemm2_kernel<<<313, 256, 0, stream>>>(h0h, h2l, Wt2h, Wt2l, b1l, gl, agg2);
    gather2_kernel<<<N_NODES / 4, 256, 0, stream>>>(cnt, rs, sPk, gl, agg2, out);
}

// Round 14
// 119.897 us; speedup vs baseline: 7.9277x; 7.9277x over previous
//
#include <hip/hip_runtime.h>
#include <math.h>

#define N_NODES 40000
#define N_EDGES 640000
#define BCAP 48                     // bucket capacity per dst (P(deg>48) ~ 1e-11; 192B rows, 64B-aligned)
#define FGRP 8                      // fill dst-range groups (XCD-affine)
#define FRANGE (N_NODES / FGRP)     // 5000 dst per group
#define NCHUNK (N_EDGES / 256)      // 2500 edge chunks
#define NSG 5084                    // supergroups of 3: 2 combo + 1 fill

typedef __attribute__((ext_vector_type(8))) short short8;   // 8 bf16 (A/B frag)
typedef __attribute__((ext_vector_type(4))) float f32x4;    // C/D frag

__device__ __forceinline__ unsigned short f2bf(float f) {
    union { float f; unsigned u; } v; v.f = f;
    unsigned r = (v.u + 0x7FFFu + ((v.u >> 16) & 1u)) >> 16;  // RNE
    return (unsigned short)r;
}
__device__ __forceinline__ float bf2f(unsigned short h) {
    union { unsigned u; float f; } v; v.u = ((unsigned)h) << 16;
    return v.f;
}

__device__ __forceinline__ float wave_sum(float v) {
    #pragma unroll
    for (int m = 1; m < 64; m <<= 1) v += __shfl_xor(v, m, 64);
    return v;
}
__device__ __forceinline__ float wave_max(float v) {
    #pragma unroll
    for (int m = 1; m < 64; m <<= 1) v = fmaxf(v, __shfl_xor(v, m, 64));
    return v;
}

// Supergroup-3 interleave: bid%3<2 -> combo (LN0 rows / weight prep)
//                          bid%3==2 -> fill (dst group g = bid&7, 4-chunk loop)
// Scatter fill with global atomics is the measured floor for this phase:
// R11 (NT hints) and R13 (LDS counting sort) both regressed.
__global__ __launch_bounds__(256) void comboFill_kernel(const float* __restrict__ x,
        const float* __restrict__ g, const float* __restrict__ b,
        unsigned short* __restrict__ h0h,
        const float* __restrict__ W0l, const float* __restrict__ W0r,
        const float* __restrict__ W1l, const float* __restrict__ W1r,
        unsigned short* __restrict__ Wt1h, unsigned short* __restrict__ Wt1l,
        unsigned short* __restrict__ Wt2h, unsigned short* __restrict__ Wt2l,
        const int* __restrict__ ei, const float* __restrict__ ew,
        int* __restrict__ cnt, unsigned int* __restrict__ sPk) {
    int bid = blockIdx.x;
    int ph = bid % 3;
    if (ph < 2) {
        int cb = (bid / 3) * 2 + ph;              // 0..10167
        if (cb < 10000) {
            int row = cb * 4 + (threadIdx.x >> 6);
            int lane = threadIdx.x & 63;
            float2 v = ((const float2*)(x + (size_t)row * 128))[lane];
            float mu = wave_sum(v.x + v.y) * (1.0f / 128.0f);
            float dx = v.x - mu, dy = v.y - mu;
            float var = wave_sum(dx * dx + dy * dy) * (1.0f / 128.0f);
            float rs = rsqrtf(var + 1e-5f);
            float2 gv = ((const float2*)g)[lane];
            float2 bv = ((const float2*)b)[lane];
            ushort2 hv;
            hv.x = f2bf(dx * rs * gv.x + bv.x);
            hv.y = f2bf(dy * rs * gv.y + bv.y);
            ((ushort2*)(h0h + (size_t)row * 128))[lane] = hv;
        } else {
            int i = (cb - 10000) * 256 + threadIdx.x;   // 0..43007
            float w; unsigned short *ph2, *pl; int idx;
            if (i < 256 * 128) {
                int c = i >> 7, k = i & 127;
                w = (c < 128) ? W0l[c * 128 + k] : W0r[(c - 128) * 128 + k];
                ph2 = Wt1h; pl = Wt1l; idx = i;
            } else {
                int j = i - 256 * 128;
                int c = j >> 7, k = j & 127;
                w = (c < 40) ? W1l[c * 128 + k] : W1r[(c - 40) * 128 + k];
                ph2 = Wt2h; pl = Wt2l; idx = j;
            }
            unsigned short hi = f2bf(w);
            ph2[idx] = hi;
            pl[idx] = f2bf(w - bf2f(hi));
        }
    } else {
        int gp = bid & 7;                         // XCD-affine dst group
        int j = (bid / 3) >> 3;                   // 0..635
        int lo = gp * FRANGE;
        #pragma unroll
        for (int cc = 0; cc < 4; ++cc) {
            int chunk = j * 4 + cc;
            if (chunk < NCHUNK) {
                int e = chunk * 256 + threadIdx.x;
                int d = ei[N_EDGES + e];
                if (d >= lo && d < lo + FRANGE) {
                    unsigned int pk = (unsigned int)ei[e] | ((unsigned int)f2bf(ew[e]) << 16);
                    int rank = atomicAdd(&cnt[d], 1);
                    if (rank < BCAP) sPk[(size_t)d * BCAP + rank] = pk;
                }
            }
        }
    }
}

// ---------------- MFMA GEMMs, B staged in LDS (XOR-swizzled) ----------------
// LDS element (c,k) at byte (c*256 + k*2) ^ ((c&7)<<4).
// C/D: col = lane&15, row = (lane>>4)*4 + reg   [HW-verified]

// bf16x2 (Ah·Bh + Ah·Bl): hl(bf16,+bias) cols 0..127; agg(bf16) cols 128..255
__global__ __launch_bounds__(256) void gemm1_kernel(
        const unsigned short* __restrict__ h0h,
        const unsigned short* __restrict__ Wt1h, const unsigned short* __restrict__ Wt1l,
        const float* __restrict__ b0l,
        unsigned short* __restrict__ hl, unsigned short* __restrict__ agg) {
    __shared__ unsigned short Bs[2][128 * 128];   // 64 KB
    int tid = threadIdx.x;
    int cBase = blockIdx.y * 128;
    #pragma unroll
    for (int plane = 0; plane < 2; ++plane) {
        const unsigned short* src = plane ? Wt1l : Wt1h;
        char* dst = (char*)Bs[plane];
        #pragma unroll
        for (int i = 0; i < 8; ++i) {
            int gid = i * 256 + tid;
            int c = gid >> 4, kc = gid & 15;
            short8 v = *(const short8*)(src + (size_t)(cBase + c) * 128 + kc * 8);
            int byte = (c * 256 + kc * 16) ^ ((c & 7) << 4);
            *(short8*)(dst + byte) = v;
        }
    }
    __syncthreads();

    int wid = tid >> 6, lane = tid & 63;
    int rBase = (blockIdx.x * 4 + wid) * 32;
    if (rBase < N_NODES) {
        int lr = lane & 15;
        int lk = (lane >> 4) * 8;
        int sw = (lr & 7) << 4;
        const unsigned short* a0h = h0h + (size_t)(rBase + lr) * 128 + lk;
        const unsigned short* a1h = a0h + 16 * 128;
        f32x4 acc[2][8] = {};
        #pragma unroll
        for (int ks = 0; ks < 4; ++ks) {
            int kb = ks * 32;
            short8 A0h = *(const short8*)(a0h + kb);
            short8 A1h = *(const short8*)(a1h + kb);
            #pragma unroll
            for (int ct = 0; ct < 8; ++ct) {
                int bb = (((ct * 16 + lr) << 8) + (ks << 6) + ((lane >> 4) << 4)) ^ sw;
                short8 Bh = *(const short8*)((const char*)Bs[0] + bb);
                short8 Bl = *(const short8*)((const char*)Bs[1] + bb);
                acc[0][ct] = __builtin_amdgcn_mfma_f32_16x16x32_bf16(A0h, Bh, acc[0][ct], 0, 0, 0);
                acc[0][ct] = __builtin_amdgcn_mfma_f32_16x16x32_bf16(A0h, Bl, acc[0][ct], 0, 0, 0);
                acc[1][ct] = __builtin_amdgcn_mfma_f32_16x16x32_bf16(A1h, Bh, acc[1][ct], 0, 0, 0);
                acc[1][ct] = __builtin_amdgcn_mfma_f32_16x16x32_bf16(A1h, Bl, acc[1][ct], 0, 0, 0);
            }
        }
        int orow = (lane >> 4) * 4;
        #pragma unroll
        for (int rt = 0; rt < 2; ++rt) {
            int row = rBase + rt * 16 + orow;
            #pragma unroll
            for (int ct = 0; ct < 8; ++ct) {
                int col = cBase + ct * 16 + lr;
                if (col < 128) {
                    float bias = b0l[col];
                    #pragma unroll
                    for (int j = 0; j < 4; ++j)
                        hl[(size_t)(row + j) * 128 + col] = f2bf(acc[rt][ct][j] + bias);
                } else {
                    int cc = col - 128;
                    #pragma unroll
                    for (int j = 0; j < 4; ++j)
                        agg[(size_t)(row + j) * 128 + cc] = f2bf(acc[rt][ct][j]);
                }
            }
        }
    }
}

// layer-2 keeps bf16x3 (h2 hi/lo): gl(bf16,+bias) cols 0..39; agg2(bf16) cols 40..79
__global__ __launch_bounds__(256) void gemm2_kernel(
        const unsigned short* __restrict__ h2h, const unsigned short* __restrict__ h2l,
        const unsigned short* __restrict__ Wt2h, const unsigned short* __restrict__ Wt2l,
        const float* __restrict__ b1l,
        unsigned short* __restrict__ gl, unsigned short* __restrict__ agg2) {
    __shared__ unsigned short Bs[2][80 * 128];    // 40 KB
    int tid = threadIdx.x;
    #pragma unroll
    for (int plane = 0; plane < 2; ++plane) {
        const unsigned short* src = plane ? Wt2l : Wt2h;
        char* dst = (char*)Bs[plane];
        #pragma unroll
        for (int i = 0; i < 5; ++i) {
            int gid = i * 256 + tid;
            int c = gid >> 4, kc = gid & 15;
            short8 v = *(const short8*)(src + (size_t)c * 128 + kc * 8);
            int byte = (c * 256 + kc * 16) ^ ((c & 7) << 4);
            *(short8*)(dst + byte) = v;
        }
    }
    __syncthreads();

    int wid = tid >> 6, lane = tid & 63;
    int rBase = (blockIdx.x * 4 + wid) * 32;
    if (rBase < N_NODES) {
        int lr = lane & 15;
        int lk = (lane >> 4) * 8;
        int sw = (lr & 7) << 4;
        const unsigned short* a0h = h2h + (size_t)(rBase + lr) * 128 + lk;
        const unsigned short* a0l = h2l + (size_t)(rBase + lr) * 128 + lk;
        const unsigned short* a1h = a0h + 16 * 128;
        const unsigned short* a1l = a0l + 16 * 128;
        f32x4 acc[2][5] = {};
        #pragma unroll
        for (int ks = 0; ks < 4; ++ks) {
            int kb = ks * 32;
            short8 A0h = *(const short8*)(a0h + kb);
            short8 A0l = *(const short8*)(a0l + kb);
            short8 A1h = *(const short8*)(a1h + kb);
            short8 A1l = *(const short8*)(a1l + kb);
            #pragma unroll
            for (int ct = 0; ct < 5; ++ct) {
                int bb = (((ct * 16 + lr) << 8) + (ks << 6) + ((lane >> 4) << 4)) ^ sw;
                short8 Bh = *(const short8*)((const char*)Bs[0] + bb);
                short8 Bl = *(const short8*)((const char*)Bs[1] + bb);
                acc[0][ct] = __builtin_amdgcn_mfma_f32_16x16x32_bf16(A0h, Bh, acc[0][ct], 0, 0, 0);
                acc[0][ct] = __builtin_amdgcn_mfma_f32_16x16x32_bf16(A0h, Bl, acc[0][ct], 0, 0, 0);
                acc[0][ct] = __builtin_amdgcn_mfma_f32_16x16x32_bf16(A0l, Bh, acc[0][ct], 0, 0, 0);
                acc[1][ct] = __builtin_amdgcn_mfma_f32_16x16x32_bf16(A1h, Bh, acc[1][ct], 0, 0, 0);
                acc[1][ct] = __builtin_amdgcn_mfma_f32_16x16x32_bf16(A1h, Bl, acc[1][ct], 0, 0, 0);
                acc[1][ct] = __builtin_amdgcn_mfma_f32_16x16x32_bf16(A1l, Bh, acc[1][ct], 0, 0, 0);
            }
        }
        int orow = (lane >> 4) * 4;
        #pragma unroll
        for (int rt = 0; rt < 2; ++rt) {
            int row = rBase + rt * 16 + orow;
            #pragma unroll
            for (int ct = 0; ct < 5; ++ct) {
                int col = ct * 16 + lr;   // 0..79
                if (col < 40) {
                    float bias = b1l[col];
                    #pragma unroll
                    for (int j = 0; j < 4; ++j)
                        gl[(size_t)(row + j) * 40 + col] = f2bf(acc[rt][ct][j] + bias);
                } else {
                    int cc = col - 40;
                    #pragma unroll
                    for (int j = 0; j < 4; ++j)
                        agg2[(size_t)(row + j) * 40 + cc] = f2bf(acc[rt][ct][j]);
                }
            }
        }
    }
}

__device__ __forceinline__ void g1_edge(const unsigned short* __restrict__ hl,
        unsigned int pk, int lane, float2* acc) {
    ushort2 u = ((const ushort2*)(hl + (size_t)(pk & 0xFFFF) * 128))[lane];
    float w = bf2f((unsigned short)(pk >> 16));
    acc->x = fmaf(bf2f(u.x), w, acc->x);
    acc->y = fmaf(bf2f(u.y), w, acc->y);
}

// gather (bucket layout, XCD-aligned rows) + fused l2norm+LN+relu -> split-bf16 h2
__global__ __launch_bounds__(256) void gather1_kernel(const int* __restrict__ cnt,
        const unsigned int* __restrict__ sPk, const unsigned short* __restrict__ hl,
        const unsigned short* __restrict__ agg,
        const float* __restrict__ g, const float* __restrict__ b,
        unsigned short* __restrict__ h2h, unsigned short* __restrict__ h2l) {
    int bid = blockIdx.x;
    int row = (bid & 7) * FRANGE + (bid >> 3) * 4 + (threadIdx.x >> 6);
    int lane = threadIdx.x & 63;
    int n = cnt[row]; n = n > BCAP ? BCAP : n;
    const unsigned int* ep = sPk + (size_t)row * BCAP;
    ushort2 r0 = ((const ushort2*)(agg + (size_t)row * 128))[lane];   // root (bf16)
    float2 acc; acc.x = bf2f(r0.x); acc.y = bf2f(r0.y);
    int e = 0;
    for (; e + 8 <= n; e += 8) {
        uint4 q0 = *(const uint4*)(ep + e);
        uint4 q1 = *(const uint4*)(ep + e + 4);
        g1_edge(hl, q0.x, lane, &acc); g1_edge(hl, q0.y, lane, &acc);
        g1_edge(hl, q0.z, lane, &acc); g1_edge(hl, q0.w, lane, &acc);
        g1_edge(hl, q1.x, lane, &acc); g1_edge(hl, q1.y, lane, &acc);
        g1_edge(hl, q1.z, lane, &acc); g1_edge(hl, q1.w, lane, &acc);
    }
    if (e + 4 <= n) {
        uint4 q0 = *(const uint4*)(ep + e);
        g1_edge(hl, q0.x, lane, &acc); g1_edge(hl, q0.y, lane, &acc);
        g1_edge(hl, q0.z, lane, &acc); g1_edge(hl, q0.w, lane, &acc);
        e += 4;
    }
    for (; e < n; ++e) g1_edge(hl, ep[e], lane, &acc);
    float nrm = sqrtf(wave_sum(acc.x * acc.x + acc.y * acc.y));
    float inv = 1.0f / fmaxf(nrm, 1e-12f);
    float vx = acc.x * inv, vy = acc.y * inv;
    float mu = wave_sum(vx + vy) * (1.0f / 128.0f);
    float dx = vx - mu, dy = vy - mu;
    float var = wave_sum(dx * dx + dy * dy) * (1.0f / 128.0f);
    float rs = rsqrtf(var + 1e-5f);
    float2 gv = ((const float2*)g)[lane];
    float2 bv = ((const float2*)b)[lane];
    float ox = fmaxf(dx * rs * gv.x + bv.x, 0.0f);
    float oy = fmaxf(dy * rs * gv.y + bv.y, 0.0f);
    ushort2 hv, lv;
    hv.x = f2bf(ox); hv.y = f2bf(oy);
    lv.x = f2bf(ox - bf2f(hv.x)); lv.y = f2bf(oy - bf2f(hv.y));
    ((ushort2*)(h2h + (size_t)row * 128))[lane] = hv;
    ((ushort2*)(h2l + (size_t)row * 128))[lane] = lv;
}

// gather (bucket layout, XCD-aligned rows) + fused l2norm + log_softmax
__global__ __launch_bounds__(256) void gather2_kernel(const int* __restrict__ cnt,
        const unsigned int* __restrict__ sPk, const unsigned short* __restrict__ gl,
        const unsigned short* __restrict__ agg2, float* __restrict__ out) {
    int bid = blockIdx.x;
    int row = (bid & 7) * FRANGE + (bid >> 3) * 4 + (threadIdx.x >> 6);
    int lane = threadIdx.x & 63;
    bool act = lane < 40;
    int n = cnt[row]; n = n > BCAP ? BCAP : n;
    const unsigned int* ep = sPk + (size_t)row * BCAP;
    float acc = act ? bf2f(agg2[(size_t)row * 40 + lane]) : 0.0f;  // root (bf16)
    int e = 0;
    for (; e + 8 <= n; e += 8) {
        uint4 q0 = *(const uint4*)(ep + e);
        uint4 q1 = *(const uint4*)(ep + e + 4);
        if (act) {
            float v0 = bf2f(gl[(size_t)(q0.x & 0xFFFF) * 40 + lane]);
            float v1 = bf2f(gl[(size_t)(q0.y & 0xFFFF) * 40 + lane]);
            float v2 = bf2f(gl[(size_t)(q0.z & 0xFFFF) * 40 + lane]);
            float v3 = bf2f(gl[(size_t)(q0.w & 0xFFFF) * 40 + lane]);
            float v4 = bf2f(gl[(size_t)(q1.x & 0xFFFF) * 40 + lane]);
            float v5 = bf2f(gl[(size_t)(q1.y & 0xFFFF) * 40 + lane]);
            float v6 = bf2f(gl[(size_t)(q1.z & 0xFFFF) * 40 + lane]);
            float v7 = bf2f(gl[(size_t)(q1.w & 0xFFFF) * 40 + lane]);
            acc = fmaf(v0, bf2f((unsigned short)(q0.x >> 16)), acc);
            acc = fmaf(v1, bf2f((unsigned short)(q0.y >> 16)), acc);
            acc = fmaf(v2, bf2f((unsigned short)(q0.z >> 16)), acc);
            acc = fmaf(v3, bf2f((unsigned short)(q0.w >> 16)), acc);
            acc = fmaf(v4, bf2f((unsigned short)(q1.x >> 16)), acc);
            acc = fmaf(v5, bf2f((unsigned short)(q1.y >> 16)), acc);
            acc = fmaf(v6, bf2f((unsigned short)(q1.z >> 16)), acc);
            acc = fmaf(v7, bf2f((unsigned short)(q1.w >> 16)), acc);
        }
    }
    if (e + 4 <= n) {
        uint4 q0 = *(const uint4*)(ep + e);
        if (act) {
            float v0 = bf2f(gl[(size_t)(q0.x & 0xFFFF) * 40 + lane]);
            float v1 = bf2f(gl[(size_t)(q0.y & 0xFFFF) * 40 + lane]);
            float v2 = bf2f(gl[(size_t)(q0.z & 0xFFFF) * 40 + lane]);
            float v3 = bf2f(gl[(size_t)(q0.w & 0xFFFF) * 40 + lane]);
            acc = fmaf(v0, bf2f((unsigned short)(q0.x >> 16)), acc);
            acc = fmaf(v1, bf2f((unsigned short)(q0.y >> 16)), acc);
            acc = fmaf(v2, bf2f((unsigned short)(q0.z >> 16)), acc);
            acc = fmaf(v3, bf2f((unsigned short)(q0.w >> 16)), acc);
        }
        e += 4;
    }
    for (; e < n; ++e) {
        unsigned int p = ep[e];
        if (act) {
            float v = bf2f(gl[(size_t)(p & 0xFFFF) * 40 + lane]);
            acc = fmaf(v, bf2f((unsigned short)(p >> 16)), acc);
        }
    }
    float nrm = sqrtf(wave_sum(act ? acc * acc : 0.0f));
    float o = acc / fmaxf(nrm, 1e-12f);
    float m = wave_max(act ? o : -INFINITY);
    float s = wave_sum(act ? expf(o - m) : 0.0f);
    float ls = logf(s);
    if (act) out[(size_t)row * 40 + lane] = o - m - ls;
}

extern "C" void kernel_launch(void* const* d_in, const int* in_sizes, int n_in,
                              void* d_out, int out_size, void* d_ws, size_t ws_size,
                              hipStream_t stream) {
    const float* x    = (const float*)d_in[0];
    const int*   ei   = (const int*)d_in[1];
    const float* ew   = (const float*)d_in[2];
    const float* ln0g = (const float*)d_in[3];
    const float* ln0b = (const float*)d_in[4];
    const float* W0l  = (const float*)d_in[5];
    const float* b0l  = (const float*)d_in[6];
    const float* W0r  = (const float*)d_in[7];
    const float* ln1g = (const float*)d_in[8];
    const float* ln1b = (const float*)d_in[9];
    const float* W1l  = (const float*)d_in[10];
    const float* b1l  = (const float*)d_in[11];
    const float* W1r  = (const float*)d_in[12];
    float* out = (float*)d_out;

    const size_t NBUF = (size_t)N_NODES * 128;  // 5.12M elems
    char* p = (char*)d_ws;
    auto alloc = [&](size_t bytes) { char* r = p; p += (bytes + 255) & ~(size_t)255; return r; };
    unsigned short* agg  = (unsigned short*)alloc(NBUF * 2); // agg / agg2 (bf16)
    unsigned short* hl   = (unsigned short*)alloc(NBUF * 2); // hl / gl (bf16)
    unsigned short* h0h  = (unsigned short*)alloc(NBUF * 2); // h0 (1 plane) / h2 hi
    unsigned short* h2l  = (unsigned short*)alloc(NBUF * 2); // h2 lo
    unsigned short* Wt1h = (unsigned short*)alloc(256 * 128 * 2);
    unsigned short* Wt1l = (unsigned short*)alloc(256 * 128 * 2);
    unsigned short* Wt2h = (unsigned short*)alloc(80 * 128 * 2);
    unsigned short* Wt2l = (unsigned short*)alloc(80 * 128 * 2);
    unsigned int*   sPk  = (unsigned int*)alloc((size_t)N_NODES * BCAP * 4); // 7.68 MB
    int*            cnt  = (int*)alloc(N_NODES * 4);
    unsigned short* gl   = hl;    // hl dead after gather1 (stride 40, 3.2MB L2-resident)
    unsigned short* agg2 = agg;   // agg dead after gather1

    // 1. zero bucket counters
    hipMemsetAsync(cnt, 0, (size_t)N_NODES * 4, stream);
    // 2. fused LN0 + weight prep + bucket-fill (interleaved, XCD-affine fill)
    comboFill_kernel<<<NSG * 3, 256, 0, stream>>>(x, ln0g, ln0b, h0h,
            W0l, W0r, W1l, W1r, Wt1h, Wt1l, Wt2h, Wt2l, ei, ew, cnt, sPk);
    // 3-6. pipeline
    gemm1_kernel<<<dim3(313, 2), 256, 0, stream>>>(h0h, Wt1h, Wt1l, b0l, hl, agg);
    gather1_kernel<<<N_NODES / 4, 256, 0, stream>>>(cnt, sPk, hl, agg,
                                                    ln1g, ln1b, h0h, h2l);
    gemm2_kernel<<<313, 256, 0, stream>>>(h0h, h2l, Wt2h, Wt2l, b1l, gl, agg2);
    gather2_kernel<<<N_NODES / 4, 256, 0, stream>>>(cnt, sPk, gl, agg2, out);
}